// Round 7
// baseline (350.631 us; speedup 1.0000x reference)
//
#include <hip/hip_runtime.h>
#include <cstddef>
#include <cstdint>

// LinearAttention B=4,S=4096,D=1024,H=16,Hd=64.  M=16384.
// Round 9: fuse y + output GEMM (eliminates yb 32MB write + 32MB read + one
// launch).  gemm_qkv_256 / kv_ksum / reduce_kv / prep unchanged from R6
// (verified 327.0us, qkv 112.2us clean).
//  - y_out_fused: grid 256 (out tiles 256x256, XCD-swizzled so 4 nt-blocks
//    of one mt are adjacent -> qf_h L2-reuse).  Per h: stage qf_h/wot_h/kv_h
//    -> y_h per wave (16+4 MFMA, z via replicated-ksum B) -> y_h to LDS
//    (swizzled) -> 64 out-MFMA into persistent acc[8][4].

typedef __attribute__((ext_vector_type(8))) __bf16 bf16x8;
typedef __attribute__((ext_vector_type(4))) __bf16 bf16x4;
typedef __attribute__((ext_vector_type(2))) __bf16 bf16x2;
typedef __attribute__((ext_vector_type(4))) float f32x4;

__device__ __forceinline__ void async_cp16(const void* g, void* s) {
    __builtin_amdgcn_global_load_lds(
        (__attribute__((address_space(1))) void*)g,
        (__attribute__((address_space(3))) void*)s, 16, 0, 0);
}

#define MFMA16(d, a, b) \
    d = __builtin_amdgcn_mfma_f32_16x16x32_bf16(a, b, d, 0, 0, 0)

// ---------------------------------------------------------------------------
// 256x256 C-tile core (R6, verified): A[.,1024] x BT[1024,1024]^T, BK=64,
// 512 threads = 8 waves (2Mx4N).  LDS 128KiB dbuf.  Swizzle row r chunk
// s^(r&7) via pre-swizzled global source; reads XOR chunk with (fr&7).
// Schedule per K-tile (one barrier/phase, drain after MFMA):
//   p0: reads aR1(T),bC1(T)[bc];  stage Bh1(T+1)->bn | MFMA r0c0
//   p1: vmcnt(4);                 stage Ah0(T+2)->bc | MFMA r0c1
//   p2: vmcnt(2); reads aR0(T+1)[bn]; stage Ah1(T+2) | MFMA r1c0
//   p3: reads bC0(T+1)[bn];       stage Bh0(T+2)->bc | MFMA r1c1
// T=14 uses vmcnt(0)@p2 (covers Bh1(15)); T=15 drains.
// ---------------------------------------------------------------------------

#define QUAD(ARR, BRR, RO, CO)                                                 \
    _Pragma("unroll")                                                          \
    for (int _qi = 0; _qi < 4; ++_qi)                                          \
        _Pragma("unroll")                                                      \
        for (int _qj = 0; _qj < 2; ++_qj)                                      \
            _Pragma("unroll")                                                  \
            for (int _qk = 0; _qk < 2; ++_qk)                                  \
                acc[(RO) + _qi][(CO) + _qj] =                                  \
                    __builtin_amdgcn_mfma_f32_16x16x32_bf16(                   \
                        ARR[_qi][_qk], BRR[_qj][_qk],                          \
                        acc[(RO) + _qi][(CO) + _qj], 0, 0, 0);

__device__ __forceinline__ void mfma256_core(const __bf16* __restrict__ A,
                                             const __bf16* __restrict__ BT,
                                             int mbase, int nbase,
                                             f32x4 acc[8][4])
{
    extern __shared__ __bf16 lds[];
    const int t    = threadIdx.x;
    const int lane = t & 63;
    const int wid  = t >> 6;
    const int wm   = wid >> 2;
    const int wn   = wid & 3;
    const int fr   = lane & 15;
    const int fq   = lane >> 4;
    const int srow  = lane >> 3;
    const int sslot = ((lane & 7) ^ srow) << 3;

    const __bf16* aBase = A  + (size_t)mbase * 1024;
    const __bf16* bBase = BT + (size_t)nbase * 1024;

#define STAGE_AH(tile, hh, bb)                                                 \
    { _Pragma("unroll") for (int _i = 0; _i < 2; ++_i) {                       \
          const int _c = 2 * wid + _i;                                         \
          async_cp16(aBase + (size_t)((hh) * 128 + _c * 8 + srow) * 1024       \
                         + (tile) * 64 + sslot,                                \
                     lds + (bb) * 32768 + (hh) * 8192 + _c * 512); } }
#define STAGE_BH(tile, hh, bb)                                                 \
    { _Pragma("unroll") for (int _i = 0; _i < 2; ++_i) {                       \
          const int _c = 2 * wid + _i;                                         \
          async_cp16(bBase + (size_t)((hh) * 128 + _c * 8 + srow) * 1024       \
                         + (tile) * 64 + sslot,                                \
                     lds + (bb) * 32768 + 16384 + (hh) * 8192 + _c * 512); } }
#define LDA(ri, ks, b)                                                         \
    (*(const bf16x8*)(lds + (b) * 32768 + (wm * 128 + (ri) * 16 + fr) * 64     \
                      + (((ks) * 32 + fq * 8) ^ ((fr & 7) << 3))))
#define LDB(cj, ks, b)                                                         \
    (*(const bf16x8*)(lds + (b) * 32768 + 16384                                \
                      + (wn * 64 + (cj) * 16 + fr) * 64                        \
                      + (((ks) * 32 + fq * 8) ^ ((fr & 7) << 3))))

#define PHASE_END                                                              \
    asm volatile("s_waitcnt lgkmcnt(0)" ::: "memory");                         \
    __builtin_amdgcn_s_barrier();

#define KTILE(T, BC, BN, S2, NX, P2W)                                          \
    {                                                                          \
        _Pragma("unroll") for (int _i = 0; _i < 4; ++_i) {                     \
            aR1[_i][0] = LDA(4 + _i, 0, BC);                                   \
            aR1[_i][1] = LDA(4 + _i, 1, BC);                                   \
        }                                                                      \
        _Pragma("unroll") for (int _j = 0; _j < 2; ++_j) {                     \
            bC1[_j][0] = LDB(2 + _j, 0, BC);                                   \
            bC1[_j][1] = LDB(2 + _j, 1, BC);                                   \
        }                                                                      \
        if (NX) STAGE_BH((T) + 1, 1, BN)                                       \
        __builtin_amdgcn_sched_barrier(0);                                     \
        __builtin_amdgcn_s_setprio(1);                                         \
        QUAD(aR0, bC0, 0, 0)                                                   \
        __builtin_amdgcn_s_setprio(0);                                         \
        PHASE_END                                                              \
        if (NX) asm volatile("s_waitcnt vmcnt(4)" ::: "memory");               \
        if (S2) STAGE_AH((T) + 2, 0, BC)                                       \
        __builtin_amdgcn_sched_barrier(0);                                     \
        __builtin_amdgcn_s_setprio(1);                                         \
        QUAD(aR0, bC1, 0, 2)                                                   \
        __builtin_amdgcn_s_setprio(0);                                         \
        PHASE_END                                                              \
        if (NX) asm volatile("s_waitcnt vmcnt(" P2W ")" ::: "memory");         \
        if (NX) {                                                              \
            _Pragma("unroll") for (int _i = 0; _i < 4; ++_i) {                 \
                aR0[_i][0] = LDA(_i, 0, BN);                                   \
                aR0[_i][1] = LDA(_i, 1, BN);                                   \
            }                                                                  \
        }                                                                      \
        if (S2) STAGE_AH((T) + 2, 1, BC)                                       \
        __builtin_amdgcn_sched_barrier(0);                                     \
        __builtin_amdgcn_s_setprio(1);                                         \
        QUAD(aR1, bC0, 4, 0)                                                   \
        __builtin_amdgcn_s_setprio(0);                                         \
        PHASE_END                                                              \
        if (NX) {                                                              \
            _Pragma("unroll") for (int _j = 0; _j < 2; ++_j) {                 \
                bC0[_j][0] = LDB(_j, 0, BN);                                   \
                bC0[_j][1] = LDB(_j, 1, BN);                                   \
            }                                                                  \
        }                                                                      \
        if (S2) STAGE_BH((T) + 2, 0, BC)                                       \
        __builtin_amdgcn_sched_barrier(0);                                     \
        __builtin_amdgcn_s_setprio(1);                                         \
        QUAD(aR1, bC1, 4, 2)                                                   \
        __builtin_amdgcn_s_setprio(0);                                         \
        PHASE_END                                                              \
    }

    bf16x8 aR0[4][2], aR1[4][2], bC0[2][2], bC1[2][2];

    STAGE_AH(0, 0, 0) STAGE_AH(0, 1, 0) STAGE_BH(0, 0, 0) STAGE_BH(0, 1, 0)
    STAGE_AH(1, 0, 1) STAGE_AH(1, 1, 1) STAGE_BH(1, 0, 1)
    asm volatile("s_waitcnt vmcnt(6)" ::: "memory");
    __builtin_amdgcn_s_barrier();

#pragma unroll
    for (int i = 0; i < 4; ++i) {
        aR0[i][0] = LDA(i, 0, 0);
        aR0[i][1] = LDA(i, 1, 0);
    }
#pragma unroll
    for (int j = 0; j < 2; ++j) {
        bC0[j][0] = LDB(j, 0, 0);
        bC0[j][1] = LDB(j, 1, 0);
    }

    for (int T = 0; T < 14; ++T) {
        const int bc = T & 1, bn = bc ^ 1;
        KTILE(T, bc, bn, 1, 1, "2")
    }
    KTILE(14, 0, 1, 0, 1, "0")
    KTILE(15, 1, 0, 0, 0, "0")

#undef KTILE
#undef PHASE_END
#undef STAGE_AH
#undef STAGE_BH
#undef LDA
#undef LDB
}

// ---------------------------------------------------------------------------
// QKV: grid=768 1-D, XCD-bijective swizzle; decode mt(64) x ntl(12);
// ntl>>2: 0=q 1=k (both elu+1) 2=v. All bf16 out.
// ---------------------------------------------------------------------------
__global__ __launch_bounds__(512) void gemm_qkv_256(
    const __bf16* __restrict__ xb,
    const __bf16* __restrict__ wqt, const __bf16* __restrict__ wkt,
    const __bf16* __restrict__ wvt,
    const float* __restrict__ bq, const float* __restrict__ bk,
    const float* __restrict__ bv,
    __bf16* __restrict__ qfb, __bf16* __restrict__ kfb, __bf16* __restrict__ vb)
{
    f32x4 acc[8][4];
#pragma unroll
    for (int i = 0; i < 8; ++i)
#pragma unroll
        for (int j = 0; j < 4; ++j) acc[i][j] = (f32x4){0.f, 0.f, 0.f, 0.f};

    const int o   = blockIdx.x;
    const int swz = (o & 7) * 96 + (o >> 3);
    const int mt  = swz / 12;
    const int ntl = swz - mt * 12;

    const int which = ntl >> 2;
    const int nbase = (ntl & 3) * 256;
    const int mbase = mt * 256;

    const __bf16* BT  = (which == 0) ? wqt : (which == 1) ? wkt : wvt;
    const float* bias = (which == 0) ? bq : (which == 1) ? bk : bv;
    __bf16* outp      = (which == 0) ? qfb : (which == 1) ? kfb : vb;
    const bool feat   = (which < 2);

    mfma256_core(xb, BT, mbase, nbase, acc);

    const int t = threadIdx.x, lane = t & 63, wid = t >> 6;
    const int wm = wid >> 2, wn = wid & 3;
    const int fr = lane & 15, fq = lane >> 4;

#pragma unroll
    for (int ri = 0; ri < 8; ++ri)
#pragma unroll
        for (int cj = 0; cj < 4; ++cj) {
            const int col = nbase + wn * 64 + cj * 16 + fr;
            const float bval = bias[col];
#pragma unroll
            for (int r = 0; r < 4; ++r) {
                const int row = mbase + wm * 128 + ri * 16 + fq * 4 + r;
                float vv = acc[ri][cj][r] + bval;
                if (feat) vv = (vv > 0.f) ? (vv + 1.f) : __expf(vv);
                outp[(size_t)row * 1024 + col] = (__bf16)vv;
            }
        }
}

// ---------------------------------------------------------------------------
// y+out fused: out[256x256 tile] = sum_h (z .* (qf_h @ kv_h^T)) @ wot_h + bo
// grid=256 1-D (XCD swizzle, 4 nt-blocks of one mt adjacent).
// LDS: bufQ 32K | bufW 32K | bufY 32K | bufKV 8K = 104KiB.
// All LDS addressing uses row*64 + (chunk ^ ((row&7)<<3)) convention; the
// staging pre-swizzles the GLOBAL source (linear LDS dest).
// ---------------------------------------------------------------------------
__global__ __launch_bounds__(512) void y_out_fused(
    const __bf16* __restrict__ qfb, const __bf16* __restrict__ kvb,
    const __bf16* __restrict__ ksumb, const __bf16* __restrict__ wot,
    const float* __restrict__ bo, float* __restrict__ out)
{
    extern __shared__ __bf16 lds[];
    __bf16* bufQ  = lds;            // 16384 elems
    __bf16* bufW  = lds + 16384;    // 16384
    __bf16* bufY  = lds + 32768;    // 16384
    __bf16* bufKV = lds + 49152;    // 4096

    const int t = threadIdx.x, lane = t & 63, wid = t >> 6;
    const int wm = wid >> 2, wn = wid & 3;
    const int fr = lane & 15, fq = lane >> 4;
    const int srow  = lane >> 3;
    const int sslot = ((lane & 7) ^ srow) << 3;

    const int o   = blockIdx.x;
    const int swz = (o & 7) * 32 + (o >> 3);
    const int mbase = (swz >> 2) * 256;
    const int nbase = (swz & 3) * 256;
    const int batch16 = (mbase >> 12) * 16;

    const __bf16* qBase = qfb + (size_t)mbase * 1024;
    const __bf16* wBase = wot + (size_t)nbase * 1024;

    f32x4 acc[8][4];
#pragma unroll
    for (int i = 0; i < 8; ++i)
#pragma unroll
        for (int j = 0; j < 4; ++j) acc[i][j] = (f32x4){0.f, 0.f, 0.f, 0.f};

    for (int h = 0; h < 16; ++h) {
        const int bh = batch16 + h;

        // all reads of previous h complete before stage writes can land
        __syncthreads();

        // ---- stage qf_h (256x64), wot_h (256x64), kv_h (64x64) ----
#pragma unroll
        for (int hh = 0; hh < 2; ++hh)
#pragma unroll
            for (int i2 = 0; i2 < 2; ++i2) {
                const int c = 2 * wid + i2;
                async_cp16(qBase + (size_t)(hh * 128 + c * 8 + srow) * 1024
                               + h * 64 + sslot,
                           bufQ + hh * 8192 + c * 512);
                async_cp16(wBase + (size_t)(hh * 128 + c * 8 + srow) * 1024
                               + h * 64 + sslot,
                           bufW + hh * 8192 + c * 512);
            }
        {
            const int kr = t >> 3, kc = t & 7;
            async_cp16(kvb + (size_t)bh * 4096 + kr * 64
                           + ((kc ^ (kr & 7)) << 3),
                       bufKV + t * 8);
        }
        asm volatile("s_waitcnt vmcnt(0)" ::: "memory");
        __syncthreads();

        // ---- y phase: wave owns rows 32*wid .. +32 of the 256-row tile ----
        bf16x8 ksb[2];
        ksb[0] = *(const bf16x8*)(ksumb + bh * 64 + fq * 8);
        ksb[1] = *(const bf16x8*)(ksumb + bh * 64 + 32 + fq * 8);

        f32x4 yac[2][4], zac[2];
#pragma unroll
        for (int i = 0; i < 2; ++i) {
            zac[i] = (f32x4){0.f, 0.f, 0.f, 0.f};
#pragma unroll
            for (int j = 0; j < 4; ++j) yac[i][j] = (f32x4){0.f, 0.f, 0.f, 0.f};
        }

#pragma unroll
        for (int kk = 0; kk < 2; ++kk) {
            bf16x8 af[2], bkv[4];
#pragma unroll
            for (int i = 0; i < 2; ++i)
                af[i] = *(const bf16x8*)(bufQ + (32 * wid + 16 * i + fr) * 64
                             + ((kk * 32 + fq * 8) ^ ((fr & 7) << 3)));
#pragma unroll
            for (int j = 0; j < 4; ++j)
                bkv[j] = *(const bf16x8*)(bufKV + (16 * j + fr) * 64
                             + ((kk * 32 + fq * 8) ^ ((fr & 7) << 3)));
#pragma unroll
            for (int i = 0; i < 2; ++i) {
#pragma unroll
                for (int j = 0; j < 4; ++j) MFMA16(yac[i][j], af[i], bkv[j]);
                MFMA16(zac[i], af[i], ksb[kk]);
            }
        }

        // ---- scale by z, write y_h to bufY (own rows; swizzled) ----
#pragma unroll
        for (int i = 0; i < 2; ++i)
#pragma unroll
            for (int r = 0; r < 4; ++r) {
                const int row = 32 * wid + 16 * i + fq * 4 + r;
                const float z = 1.0f / (zac[i][r] + 1e-6f);
#pragma unroll
                for (int j = 0; j < 4; ++j) {
                    const int col = 16 * j + fr;
                    bufY[row * 64 + ((((col >> 3) ^ (row & 7)) << 3) | (col & 7))]
                        = (__bf16)(yac[i][j][r] * z);
                }
            }
        __syncthreads();

        // ---- out phase: acc += y_h[wave rows] @ wot_h[wave cols] ----
#pragma unroll
        for (int kk = 0; kk < 2; ++kk) {
            bf16x8 ay[8], bw[4];
#pragma unroll
            for (int ri = 0; ri < 8; ++ri)
                ay[ri] = *(const bf16x8*)(bufY + (wm * 128 + ri * 16 + fr) * 64
                             + ((kk * 32 + fq * 8) ^ ((fr & 7) << 3)));
#pragma unroll
            for (int cj = 0; cj < 4; ++cj)
                bw[cj] = *(const bf16x8*)(bufW + (wn * 64 + cj * 16 + fr) * 64
                             + ((kk * 32 + fq * 8) ^ ((fr & 7) << 3)));
#pragma unroll
            for (int ri = 0; ri < 8; ++ri)
#pragma unroll
                for (int cj = 0; cj < 4; ++cj) MFMA16(acc[ri][cj], ay[ri], bw[cj]);
        }
    }

    // ---- epilogue: + bo, fp32 store ----
#pragma unroll
    for (int ri = 0; ri < 8; ++ri)
#pragma unroll
        for (int cj = 0; cj < 4; ++cj) {
            const int col = nbase + wn * 64 + cj * 16 + fr;
            const float bval = bo[col];
#pragma unroll
            for (int r = 0; r < 4; ++r) {
                const int row = mbase + wm * 128 + ri * 16 + fq * 4 + r;
                out[(size_t)row * 1024 + col] = acc[ri][cj][r] + bval;
            }
        }
}

// ---------------------------------------------------------------------------
// kv partials: kvp[bh][chunk][m][d] = sum_{s in chunk} v[s][m]*kf[s][d]
// ksum partials via ones-A MFMA.  grid=(64 bh, 16 chunks of 256 s).
// ---------------------------------------------------------------------------
__global__ __launch_bounds__(256) void kv_ksum_mfma(
    const __bf16* __restrict__ kfb, const __bf16* __restrict__ vb,
    float* __restrict__ kvp, float* __restrict__ ksp)
{
    __shared__ __bf16 kfs[64 * 66];
    __shared__ __bf16 vs[64 * 66];

    const int bh = blockIdx.x;
    const int n = bh >> 4, h = bh & 15;
    const int chunk = blockIdx.y;
    const int t = threadIdx.x, lane = t & 63, w = t >> 6;
    const int fr = lane & 15, fq = lane >> 4;

    f32x4 acc[4];
#pragma unroll
    for (int j = 0; j < 4; j++) acc[j] = (f32x4){0.f, 0.f, 0.f, 0.f};
    f32x4 accks = (f32x4){0.f, 0.f, 0.f, 0.f};

    bf16x8 ones;
#pragma unroll
    for (int e = 0; e < 8; e++) ones[e] = (__bf16)1.0f;

    const size_t base = ((size_t)n * 4096 + (size_t)chunk * 256) * 1024 + h * 64;

    for (int tile = 0; tile < 4; tile++) {
#pragma unroll
        for (int i = 0; i < 2; i++) {
            int idx = t + i * 256;              // 0..511
            int s = idx >> 3, d0 = (idx & 7) * 8;
            bf16x8 k8 = *(const bf16x8*)(kfb + base + (size_t)(tile * 64 + s) * 1024 + d0);
            bf16x8 v8 = *(const bf16x8*)(vb  + base + (size_t)(tile * 64 + s) * 1024 + d0);
#pragma unroll
            for (int e = 0; e < 4; e++) {
                *(bf16x2*)(kfs + s * 66 + d0 + 2 * e) = (bf16x2){k8[2*e], k8[2*e+1]};
                *(bf16x2*)(vs  + s * 66 + d0 + 2 * e) = (bf16x2){v8[2*e], v8[2*e+1]};
            }
        }
        __syncthreads();

#pragma unroll
        for (int kk = 0; kk < 2; kk++) {
            bf16x8 af, bfr[4];
#pragma unroll
            for (int j = 0; j < 8; j++)
                af[j] = vs[(kk * 32 + fq * 8 + j) * 66 + 16 * w + fr];
#pragma unroll
            for (int j2 = 0; j2 < 4; j2++)
#pragma unroll
                for (int j = 0; j < 8; j++)
                    bfr[j2][j] = kfs[(kk * 32 + fq * 8 + j) * 66 + 16 * j2 + fr];
#pragma unroll
            for (int j2 = 0; j2 < 4; j2++)
                acc[j2] = __builtin_amdgcn_mfma_f32_16x16x32_bf16(
                    af, bfr[j2], acc[j2], 0, 0, 0);
            accks = __builtin_amdgcn_mfma_f32_16x16x32_bf16(
                ones, bfr[w], accks, 0, 0, 0);
        }
        __syncthreads();
    }

    const size_t pbase = ((size_t)bh * 16 + chunk) * 4096;
#pragma unroll
    for (int j2 = 0; j2 < 4; j2++)
#pragma unroll
        for (int r = 0; r < 4; r++) {
            int m = 16 * w + fq * 4 + r;
            int d = 16 * j2 + fr;
            kvp[pbase + m * 64 + d] = acc[j2][r];
        }
    if (fq == 0)
        ksp[((size_t)bh * 16 + chunk) * 64 + 16 * w + fr] = accks[0];
}

// ---------------------------------------------------------------------------
// reduce partials -> kvb bf16 [bh][m][d], ksumb bf16 [bh][d]
// ---------------------------------------------------------------------------
__global__ __launch_bounds__(256) void reduce_kv(
    const float* __restrict__ kvp, const float* __restrict__ ksp,
    __bf16* __restrict__ kvb, __bf16* __restrict__ ksumb)
{
    const int b = blockIdx.x;
    if (b < 1024) {
        int i = b * 256 + threadIdx.x;          // 0..262143
        int bh = i >> 12, md = i & 4095;
        float s = 0.f;
#pragma unroll
        for (int c = 0; c < 16; c++) s += kvp[((size_t)bh * 16 + c) * 4096 + md];
        kvb[i] = (__bf16)s;
    } else {
        int j = (b - 1024) * 256 + threadIdx.x; // 0..4095
        int bh = j >> 6, d = j & 63;
        float s = 0.f;
#pragma unroll
        for (int c = 0; c < 16; c++) s += ksp[((size_t)bh * 16 + c) * 64 + d];
        ksumb[j] = (__bf16)s;
    }
}

// ---------------------------------------------------------------------------
// prep: blocks 0..8191 = cast x->bf16; blocks 8192..12287 = transpose weights.
// ---------------------------------------------------------------------------
__global__ __launch_bounds__(256) void prep(
    const float* __restrict__ x, __bf16* __restrict__ xb,
    const float* __restrict__ w0, const float* __restrict__ w1,
    const float* __restrict__ w2, const float* __restrict__ w3,
    __bf16* __restrict__ o0, __bf16* __restrict__ o1,
    __bf16* __restrict__ o2, __bf16* __restrict__ o3)
{
    __shared__ float ld[32][33];
    const int b = blockIdx.x;
    const int t = threadIdx.x;

    if (b < 8192) {
        const size_t i = ((size_t)b * 256 + t) * 8;
        float4 a = *(const float4*)(x + i);
        float4 c = *(const float4*)(x + i + 4);
        bf16x8 o;
        o[0] = (__bf16)a.x; o[1] = (__bf16)a.y; o[2] = (__bf16)a.z; o[3] = (__bf16)a.w;
        o[4] = (__bf16)c.x; o[5] = (__bf16)c.y; o[6] = (__bf16)c.z; o[7] = (__bf16)c.w;
        *(bf16x8*)(xb + i) = o;
        return;
    }

    const int idx  = b - 8192;                  // 0..4095
    const int wsel = idx >> 10;                 // 0..3
    const int yy   = (idx >> 5) & 31;           // nbase/32
    const int xx   = idx & 31;                  // kbase/32
    const float* src = (wsel == 0) ? w0 : (wsel == 1) ? w1 : (wsel == 2) ? w2 : w3;
    __bf16* dst      = (wsel == 0) ? o0 : (wsel == 1) ? o1 : (wsel == 2) ? o2 : o3;

    const int kbase = xx * 32;
    const int nbase = yy * 32;
    const int r = t >> 3, c4 = (t & 7) * 4;

    float4 a = *(const float4*)(src + (size_t)(kbase + r) * 1024 + nbase + c4);
    ld[r][c4 + 0] = a.x; ld[r][c4 + 1] = a.y; ld[r][c4 + 2] = a.z; ld[r][c4 + 3] = a.w;
    __syncthreads();

    bf16x4 o;
    o[0] = (__bf16)ld[c4 + 0][r];
    o[1] = (__bf16)ld[c4 + 1][r];
    o[2] = (__bf16)ld[c4 + 2][r];
    o[3] = (__bf16)ld[c4 + 3][r];
    *(bf16x4*)(dst + (size_t)(nbase + r) * 1024 + kbase + c4) = o;
}

extern "C" void kernel_launch(void* const* d_in, const int* in_sizes, int n_in,
                              void* d_out, int out_size, void* d_ws, size_t ws_size,
                              hipStream_t stream)
{
    const float* x  = (const float*)d_in[0];
    const float* Wq = (const float*)d_in[1];
    const float* bq = (const float*)d_in[2];
    const float* Wk = (const float*)d_in[3];
    const float* bk = (const float*)d_in[4];
    const float* Wv = (const float*)d_in[5];
    const float* bv = (const float*)d_in[6];
    const float* Wo = (const float*)d_in[7];
    const float* bo = (const float*)d_in[8];
    float* out = (float*)d_out;

    __bf16* xb    = (__bf16*)d_ws;                   // 16777216
    __bf16* wqt   = xb + (size_t)16777216;           // 1048576 each
    __bf16* wkt   = wqt + 1048576;
    __bf16* wvt   = wkt + 1048576;
    __bf16* wot   = wvt + 1048576;
    __bf16* qfb   = wot + 1048576;                   // 16777216
    __bf16* kfb   = qfb + (size_t)16777216;          // 16777216
    __bf16* vb    = kfb + (size_t)16777216;          // 16777216
    float*  kvp   = (float*)(vb + (size_t)16777216); // 4194304 fp32 (16 MB)
    float*  ksp   = kvp + 4194304;                   // 65536 fp32
    __bf16* kvb   = (__bf16*)(ksp + 65536);          // 262144
    __bf16* ksumb = kvb + 262144;                    // 4096

    const int LDS_GEMM  = 131072;
    const int LDS_FUSED = 106496;
    (void)hipFuncSetAttribute((const void*)gemm_qkv_256,
                              hipFuncAttributeMaxDynamicSharedMemorySize, LDS_GEMM);
    (void)hipFuncSetAttribute((const void*)y_out_fused,
                              hipFuncAttributeMaxDynamicSharedMemorySize, LDS_FUSED);

    prep<<<dim3(12288), dim3(256), 0, stream>>>(
        x, xb, Wq, Wk, Wv, Wo, wqt, wkt, wvt, wot);

    gemm_qkv_256<<<dim3(768), dim3(512), LDS_GEMM, stream>>>(
        xb, wqt, wkt, wvt, bq, bk, bv, qfb, kfb, vb);
    kv_ksum_mfma<<<dim3(64, 16), dim3(256), 0, stream>>>(kfb, vb, kvp, ksp);
    reduce_kv<<<dim3(1040), dim3(256), 0, stream>>>(kvp, ksp, kvb, ksumb);
    y_out_fused<<<dim3(256), dim3(512), LDS_FUSED, stream>>>(
        qfb, kvb, ksumb, wot, bo, out);
}